// Round 1
// baseline (514.404 us; speedup 1.0000x reference)
//
#include <hip/hip_runtime.h>

#define BB 32
#define NN 8192
#define EE 256
#define NAA 16
#define NCHUNK 16
#define CHUNK 512   // NN / NCHUNK

// ---- workspace float offsets ----
#define KQ_OFF   0
#define ATT_OFF  256
#define PM_OFF   (ATT_OFF + BB*NN)           // per-(b,chunk) running max
#define PL_OFF   (PM_OFF + BB*NCHUNK)        // per-(b,chunk) exp-sum
#define PS_OFF   (PL_OFF + BB*NCHUNK)        // per-(b,chunk) weighted row-sum s[256]
#define M_OFF    (PS_OFF + BB*NCHUNK*EE)     // per-b global max
#define L_OFF    (M_OFF + BB)                // per-b global exp-sum
#define INDS_OFF (L_OFF + BB)                // selected indices (int storage)
#define WSEL_OFF (INDS_OFF + BB*NAA)         // selected weights
// total ~395584 floats = 1.6 MB

// ---- output float offsets (outs, inds, weights, barcode_out) ----
#define OUT_OUTS 0
#define OUT_INDS (BB*NAA*EE)
#define OUT_W    (OUT_INDS + BB*NAA)
#define OUT_BC   (OUT_W + BB*NAA)

// kq[f] = (1/16) * sum_e Wk[f,e] * q[e],  q[e] = sum_f barcode[f]*Wq[f,e]
__global__ __launch_bounds__(256) void prep_kernel(
    const float* __restrict__ barcode, const float* __restrict__ Wq,
    const float* __restrict__ Wk, float* __restrict__ ws) {
  __shared__ float qs[EE];
  int t = threadIdx.x;
  float acc = 0.f;
  for (int f = 0; f < EE; ++f) acc += barcode[f] * Wq[f*EE + t];
  qs[t] = acc;
  __syncthreads();
  float acc2 = 0.f;
  for (int e = 0; e < EE; ++e) acc2 += Wk[t*EE + e] * qs[e];
  ws[KQ_OFF + t] = acc2 * 0.0625f;   // 1/sqrt(256), exact pow2
}

// One pass over x: att scores + online-softmax weighted row-sum partials.
__global__ __launch_bounds__(256) void pass_a(
    const float* __restrict__ x, const float* __restrict__ mask,
    float* __restrict__ ws) {
  const int c = blockIdx.x, b = blockIdx.y;
  const int w = threadIdx.x >> 6, lane = threadIdx.x & 63;
  const float4 kq4 = ((const float4*)(ws + KQ_OFF))[lane];
  float* att = ws + ATT_OFF + (size_t)b * NN + c * CHUNK;
  const float* xb = x + ((size_t)b * NN + (size_t)c * CHUNK) * EE;
  const float* mb = mask + (size_t)b * NN + c * CHUNK;

  float m = -INFINITY, l = 0.f;
  float4 acc = {0.f, 0.f, 0.f, 0.f};
  for (int r = w; r < CHUNK; r += 4) {
    float4 xv = ((const float4*)(xb + (size_t)r * EE))[lane];
    float d = xv.x*kq4.x + xv.y*kq4.y + xv.z*kq4.z + xv.w*kq4.w;
    #pragma unroll
    for (int off = 32; off >= 1; off >>= 1) d += __shfl_xor(d, off, 64);
    float mk = mb[r];
    float a = d + ((mk == -2.0f) ? -1e9f : 0.0f);
    if (lane == 0) att[r] = a;
    float keep = (mk == -2.0f) ? 0.f : 1.f;
    if (a > m) {                      // rescale running state
      float fc = expf(m - a);         // m=-inf first iter -> fc=0
      l *= fc; acc.x *= fc; acc.y *= fc; acc.z *= fc; acc.w *= fc;
      m = a;
    }
    float p = expf(a - m) * keep;
    l += p;
    acc.x += p * xv.x; acc.y += p * xv.y; acc.z += p * xv.z; acc.w += p * xv.w;
  }
  // combine the 4 waves of this block
  __shared__ float sm[4], sl[4], ss[4][EE];
  ss[w][lane*4+0] = acc.x; ss[w][lane*4+1] = acc.y;
  ss[w][lane*4+2] = acc.z; ss[w][lane*4+3] = acc.w;
  if (lane == 0) { sm[w] = m; sl[w] = l; }
  __syncthreads();
  int t = threadIdx.x;
  float M = fmaxf(fmaxf(sm[0], sm[1]), fmaxf(sm[2], sm[3]));
  float f0 = expf(sm[0]-M), f1 = expf(sm[1]-M), f2 = expf(sm[2]-M), f3 = expf(sm[3]-M);
  ws[PS_OFF + (size_t)(b*NCHUNK + c)*EE + t] =
      f0*ss[0][t] + f1*ss[1][t] + f2*ss[2][t] + f3*ss[3][t];
  if (t == 0) {
    ws[PM_OFF + b*NCHUNK + c] = M;
    ws[PL_OFF + b*NCHUNK + c] = f0*sl[0] + f1*sl[1] + f2*sl[2] + f3*sl[3];
  }
}

// Per-batch: fold chunk partials -> M, L; barcode_out = (S/L) @ Wv
__global__ __launch_bounds__(256) void combine_kernel(
    const float* __restrict__ Wv, float* __restrict__ ws, float* __restrict__ out) {
  int b = blockIdx.x, t = threadIdx.x;
  __shared__ float sn[EE];
  float M = -INFINITY;
  for (int c = 0; c < NCHUNK; ++c) M = fmaxf(M, ws[PM_OFF + b*NCHUNK + c]);
  float S = 0.f, L = 0.f;
  for (int c = 0; c < NCHUNK; ++c) {
    float fc = expf(ws[PM_OFF + b*NCHUNK + c] - M);
    S += fc * ws[PS_OFF + (size_t)(b*NCHUNK + c)*EE + t];
    L += fc * ws[PL_OFF + b*NCHUNK + c];
  }
  sn[t] = S / L;
  if (t == 0) { ws[M_OFF + b] = M; ws[L_OFF + b] = L; }
  __syncthreads();
  float acc = 0.f;
  for (int e = 0; e < EE; ++e) acc += sn[e] * Wv[e*EE + t];
  out[OUT_BC + b*EE + t] = acc;
}

// Greedy distance-constrained top-16: iterative argmax (tie -> lowest index)
// == scanning the stable descending argsort order.
__global__ __launch_bounds__(256) void select_kernel(
    const float* __restrict__ mask, float* __restrict__ ws, float* __restrict__ out) {
  int b = blockIdx.x, t = threadIdx.x;
  __shared__ float p[NN];
  __shared__ float bv[256];
  __shared__ int   bi[256];
  __shared__ int   sel[NAA];
  __shared__ float selw[NAA];
  const float* att = ws + ATT_OFF + (size_t)b * NN;
  float M = ws[M_OFF + b], L = ws[L_OFF + b];
  for (int n = t; n < NN; n += 256) {
    float pv = expf(att[n] - M) / L;                 // att1 = softmax * m
    if (mask[(size_t)b * NN + n] == -2.0f) pv = 0.f;
    p[n] = pv;
  }
  __syncthreads();
  for (int it = 0; it < NAA; ++it) {
    float v = -2.f; int idx = NN;
    for (int n = t; n < NN; n += 256) {
      float pv = p[n];
      if (pv > v) { v = pv; idx = n; }               // ascending n -> first max kept
    }
    bv[t] = v; bi[t] = idx;
    __syncthreads();
    for (int s = 128; s >= 1; s >>= 1) {
      if (t < s) {
        float v2 = bv[t+s]; int i2 = bi[t+s];
        if (v2 > bv[t] || (v2 == bv[t] && i2 < bi[t])) { bv[t] = v2; bi[t] = i2; }
      }
      __syncthreads();
    }
    if (t == 0) {
      int id = bi[0];
      sel[it] = id; selw[it] = bv[0];
      int lo = id - 2 < 0 ? 0 : id - 2;
      int hi = id + 2 > NN-1 ? NN-1 : id + 2;
      for (int j = lo; j <= hi; ++j) p[j] = -1.f;    // block |d|<3 forever
    }
    __syncthreads();
  }
  if (t == 0) {  // sort 16 (idx, weight) pairs by idx ascending
    for (int i = 1; i < NAA; ++i) {
      int ki = sel[i]; float kw = selw[i]; int j = i - 1;
      while (j >= 0 && sel[j] > ki) { sel[j+1] = sel[j]; selw[j+1] = selw[j]; --j; }
      sel[j+1] = ki; selw[j+1] = kw;
    }
  }
  __syncthreads();
  if (t < NAA) {
    out[OUT_INDS + b*NAA + t] = (float)sel[t];
    out[OUT_W    + b*NAA + t] = selw[t];
    ((int*)(ws + INDS_OFF))[b*NAA + t] = sel[t];
    ws[WSEL_OFF + b*NAA + t] = selw[t];
  }
}

// Per (b, anchor): gather row + pos, gate through w/g, scale, LayerNorm.
__global__ __launch_bounds__(256) void final_kernel(
    const float* __restrict__ x, const float* __restrict__ g,
    const float* __restrict__ w, const float* __restrict__ ln_gamma,
    const float* __restrict__ ln_beta, const float* __restrict__ ws,
    float* __restrict__ out) {
  int a = blockIdx.x, b = blockIdx.y, f = threadIdx.x;
  __shared__ float row[EE];
  __shared__ float red[4];
  int ind = ((const int*)(ws + INDS_OFF))[b*NAA + a];
  float wt = ws[WSEL_OFF + b*NAA + a];
  float ra = (float)f / 256.0f;
  float pos = sinf((float)ind / powf(40.0f, ra));
  row[f] = x[((size_t)b * NN + ind) * EE + f] + pos;
  __syncthreads();
  const float* wa = w + (size_t)a * EE * EE;
  const float* ga = g + (size_t)a * EE * EE;
  float ow = 0.f, og = 0.f;
  for (int e = 0; e < EE; ++e) {
    float r = row[e];
    ow += r * wa[e*EE + f];
    og += r * ga[e*EE + f];
  }
  float val = ow * (1.f / (1.f + expf(-og))) * wt;
  // LayerNorm over f (two-pass for accuracy)
  int wv = f >> 6;
  float s = val;
  #pragma unroll
  for (int off = 32; off >= 1; off >>= 1) s += __shfl_xor(s, off, 64);
  if ((f & 63) == 0) red[wv] = s;
  __syncthreads();
  float mu = (red[0] + red[1] + red[2] + red[3]) * (1.f/256.f);
  __syncthreads();
  float dv = val - mu, sq = dv * dv;
  #pragma unroll
  for (int off = 32; off >= 1; off >>= 1) sq += __shfl_xor(sq, off, 64);
  if ((f & 63) == 0) red[wv] = sq;
  __syncthreads();
  float var = (red[0] + red[1] + red[2] + red[3]) * (1.f/256.f);
  out[OUT_OUTS + ((size_t)b * NAA + a) * EE + f] =
      dv * rsqrtf(var + 0.001f) * ln_gamma[f] + ln_beta[f];
}

extern "C" void kernel_launch(void* const* d_in, const int* in_sizes, int n_in,
                              void* d_out, int out_size, void* d_ws, size_t ws_size,
                              hipStream_t stream) {
  const float* x       = (const float*)d_in[0];
  const float* mask    = (const float*)d_in[1];
  const float* barcode = (const float*)d_in[2];
  const float* Wq      = (const float*)d_in[3];
  const float* Wk      = (const float*)d_in[4];
  const float* Wv      = (const float*)d_in[5];
  const float* g       = (const float*)d_in[6];
  const float* w       = (const float*)d_in[7];
  const float* gamma   = (const float*)d_in[8];
  const float* beta    = (const float*)d_in[9];
  float* out = (float*)d_out;
  float* ws  = (float*)d_ws;

  prep_kernel<<<1, 256, 0, stream>>>(barcode, Wq, Wk, ws);
  pass_a<<<dim3(NCHUNK, BB), 256, 0, stream>>>(x, mask, ws);
  combine_kernel<<<BB, 256, 0, stream>>>(Wv, ws, out);
  select_kernel<<<BB, 256, 0, stream>>>(mask, ws, out);
  final_kernel<<<dim3(NAA, BB), 256, 0, stream>>>(x, g, w, gamma, beta, ws, out);
}